// Round 4
// baseline (802.914 us; speedup 1.0000x reference)
//
#include <hip/hip_runtime.h>

// ---------------------------------------------------------------------------
// mLSTM block, MI355X. B=2,S=2048,D=1024,NH=8,DH=128.
// v3: bisect round — exact prefix-max (no online rescale) + scalar-fp32 PV.
//   K0  split x, Wout -> hi/lo ; Wcat hi/lo [2304,1024]
//   K1  gates: i_pre, log_sigmoid(f_pre)  (fp32)
//   K2  scan per (b,h): csum[s], a[t]=i[t]-csum[t], ma[t]=prefixmax(a)
//   K3  GEMM3 proj = (x_hi+x_lo)(W_hi+W_lo)^T -> proj hi/lo
//   K5  fused: MFMA QK^T (3-prod) -> P=s*exp(a-ma) -> scalar-fp32 PV
//       -> n-divide -> LayerNorm -> sigmoid(og) -> hout hi/lo
//   K6  GEMM3 y -> f32
// ---------------------------------------------------------------------------

typedef __bf16 bf16x8 __attribute__((ext_vector_type(8)));
typedef float f32x4 __attribute__((ext_vector_type(4)));
typedef unsigned short us8 __attribute__((ext_vector_type(8)));

__device__ __forceinline__ unsigned short f2bf(float f) {
    unsigned int u = __builtin_bit_cast(unsigned int, f);
    unsigned int r = u + 0x7fffu + ((u >> 16) & 1u);
    return (unsigned short)(r >> 16);
}
__device__ __forceinline__ float bf2f(unsigned short h) {
    unsigned int u = ((unsigned int)h) << 16;
    return __builtin_bit_cast(float, u);
}
__device__ __forceinline__ f32x4 mfma16(bf16x8 a, bf16x8 b, f32x4 c) {
    return __builtin_amdgcn_mfma_f32_16x16x32_bf16(a, b, c, 0, 0, 0);
}

// ---------------- K0 ----------------
__global__ __launch_bounds__(256) void k_split_bf16(const float* __restrict__ in,
                                                    unsigned short* __restrict__ hi,
                                                    unsigned short* __restrict__ lo, int n) {
    int i = blockIdx.x * 256 + threadIdx.x;
    if (i < n) {
        float f = in[i];
        unsigned short h = f2bf(f);
        hi[i] = h;
        lo[i] = f2bf(f - bf2f(h));
    }
}

__global__ __launch_bounds__(256) void build_wcat(const float* __restrict__ Wq,
                                                  const float* __restrict__ Wk,
                                                  const float* __restrict__ Wv,
                                                  const float* __restrict__ Wog,
                                                  unsigned short* __restrict__ wh,
                                                  unsigned short* __restrict__ wl) {
    int idx = blockIdx.x * 256 + threadIdx.x;
    if (idx >= 2304 * 1024) return;
    int row = idx >> 10, col = idx & 1023;
    float v;
    if (row < 1024)      v = Wq[(size_t)row * 1024 + col] * 0.08838834764831845f;
    else if (row < 1152) v = Wk[(size_t)(row - 1024) * 1024 + col];
    else if (row < 1280) v = Wv[(size_t)(row - 1152) * 1024 + col];
    else                 v = Wog[(size_t)(row - 1280) * 1024 + col];
    unsigned short h = f2bf(v);
    wh[idx] = h;
    wl[idx] = f2bf(v - bf2f(h));
}

// ---------------- K1: gates ----------------
__global__ __launch_bounds__(256) void gates_kernel(const float* __restrict__ x,
                                                    const float* __restrict__ Wi,
                                                    const float* __restrict__ bi,
                                                    const float* __restrict__ Wf,
                                                    const float* __restrict__ bfb,
                                                    float* __restrict__ ipre,
                                                    float* __restrict__ lgf) {
    int bs = blockIdx.x;
    int b = bs >> 11, s = bs & 2047;
    const float* xr = x + (size_t)bs * 1024;
    int lane = threadIdx.x & 63, w = threadIdx.x >> 6;
    const float* W = (w < 2) ? Wi : Wf;
    int h0 = (w & 1) * 4;
    float dot0 = 0.f, dot1 = 0.f, dot2 = 0.f, dot3 = 0.f;
    for (int i = lane; i < 1024; i += 64) {
        float xv = xr[i];
        dot0 += xv * W[(size_t)(h0 + 0) * 1024 + i];
        dot1 += xv * W[(size_t)(h0 + 1) * 1024 + i];
        dot2 += xv * W[(size_t)(h0 + 2) * 1024 + i];
        dot3 += xv * W[(size_t)(h0 + 3) * 1024 + i];
    }
#pragma unroll
    for (int o = 32; o; o >>= 1) {
        dot0 += __shfl_xor(dot0, o);
        dot1 += __shfl_xor(dot1, o);
        dot2 += __shfl_xor(dot2, o);
        dot3 += __shfl_xor(dot3, o);
    }
    if (lane == 0) {
        float d[4] = {dot0, dot1, dot2, dot3};
#pragma unroll
        for (int j = 0; j < 4; j++) {
            int hh = h0 + j;
            if (w < 2) {
                float z = d[j] + bi[hh];
                z = 15.f * tanhf(z * (1.f / 15.f));
                ipre[((size_t)b * 8 + hh) * 2048 + s] = z;
            } else {
                float z = d[j] + bfb[hh];
                z = 15.f * tanhf(z * (1.f / 15.f));
                lgf[((size_t)b * 8 + hh) * 2048 + s] = fminf(z, 0.f) - log1pf(expf(-fabsf(z)));
            }
        }
    }
}

// ---------------- K2: scan (csum, a, prefix-max of a) ----------------
__global__ void scan_kernel(const float* __restrict__ ipre, const float* __restrict__ lgf,
                            float* __restrict__ csum, float* __restrict__ aarr,
                            float* __restrict__ marr) {
    int bh = blockIdx.x;
    int lane = threadIdx.x;
    const float* lf = lgf + (size_t)bh * 2048;
    const float* ip = ipre + (size_t)bh * 2048;
    float* cs = csum + (size_t)bh * 2048;
    float* aa = aarr + (size_t)bh * 2048;
    float* mm = marr + (size_t)bh * 2048;
    float carry = 0.f;
    float carrym = -1e30f;
    for (int c = 0; c < 32; c++) {
        float v = lf[c * 64 + lane];
#pragma unroll
        for (int o = 1; o < 64; o <<= 1) {
            float t = __shfl_up(v, o);
            if (lane >= o) v += t;
        }
        float cval = carry + v;
        cs[c * 64 + lane] = cval;
        float a = ip[c * 64 + lane] - cval;
        aa[c * 64 + lane] = a;
        float mv = a;
#pragma unroll
        for (int o = 1; o < 64; o <<= 1) {
            float t = __shfl_up(mv, o);
            if (lane >= o) mv = fmaxf(mv, t);
        }
        float mval = fmaxf(carrym, mv);
        mm[c * 64 + lane] = mval;
        carry = __shfl(cval, 63);
        carrym = __shfl(mval, 63);
    }
}

// ---- K3/K6: 3-product GEMM  C = (Ah+Al)(Bh+Bl)^T (drop Al*Bl), f32 acc ----
__global__ __launch_bounds__(256) void gemm_bt3(const unsigned short* __restrict__ Ah,
                                                const unsigned short* __restrict__ Al,
                                                const unsigned short* __restrict__ Bh,
                                                const unsigned short* __restrict__ Bl,
                                                void* __restrict__ Cp,
                                                unsigned short* __restrict__ Clo,
                                                int K, int ldc, int c_bf16) {
    __shared__ __attribute__((aligned(16))) unsigned short Ash[64 * 40];
    __shared__ __attribute__((aligned(16))) unsigned short Asl[64 * 40];
    __shared__ __attribute__((aligned(16))) unsigned short Bsh[64 * 40];
    __shared__ __attribute__((aligned(16))) unsigned short Bsl[64 * 40];
    const int tid = threadIdx.x;
    const int lane = tid & 63, wv = tid >> 6;
    const int wr = wv >> 1, wc = wv & 1;
    const int fr = lane & 15, fg = lane >> 4;
    const int srow = tid >> 2, scol = (tid & 3) * 8;
    const size_t aoff = (size_t)(blockIdx.x * 64 + srow) * K + scol;
    const size_t boff = (size_t)(blockIdx.y * 64 + srow) * K + scol;
    f32x4 acc[2][2] = {};
    for (int kt = 0; kt < K; kt += 32) {
        us8 avh = *(const us8*)(Ah + aoff + kt);
        us8 avl = *(const us8*)(Al + aoff + kt);
        us8 bvh = *(const us8*)(Bh + boff + kt);
        us8 bvl = *(const us8*)(Bl + boff + kt);
        __syncthreads();
        *(us8*)&Ash[srow * 40 + scol] = avh;
        *(us8*)&Asl[srow * 40 + scol] = avl;
        *(us8*)&Bsh[srow * 40 + scol] = bvh;
        *(us8*)&Bsl[srow * 40 + scol] = bvl;
        __syncthreads();
        bf16x8 afh[2], afl[2], bfh[2], bfl[2];
#pragma unroll
        for (int i = 0; i < 2; i++) {
            afh[i] = __builtin_bit_cast(bf16x8, *(const us8*)&Ash[(32 * wr + 16 * i + fr) * 40 + fg * 8]);
            afl[i] = __builtin_bit_cast(bf16x8, *(const us8*)&Asl[(32 * wr + 16 * i + fr) * 40 + fg * 8]);
        }
#pragma unroll
        for (int j = 0; j < 2; j++) {
            bfh[j] = __builtin_bit_cast(bf16x8, *(const us8*)&Bsh[(32 * wc + 16 * j + fr) * 40 + fg * 8]);
            bfl[j] = __builtin_bit_cast(bf16x8, *(const us8*)&Bsl[(32 * wc + 16 * j + fr) * 40 + fg * 8]);
        }
#pragma unroll
        for (int i = 0; i < 2; i++)
#pragma unroll
            for (int j = 0; j < 2; j++) {
                acc[i][j] = mfma16(afh[i], bfh[j], acc[i][j]);
                acc[i][j] = mfma16(afh[i], bfl[j], acc[i][j]);
                acc[i][j] = mfma16(afl[i], bfh[j], acc[i][j]);
            }
    }
#pragma unroll
    for (int i = 0; i < 2; i++)
#pragma unroll
        for (int j = 0; j < 2; j++)
#pragma unroll
            for (int e = 0; e < 4; e++) {
                int r = blockIdx.x * 64 + 32 * wr + 16 * i + fg * 4 + e;
                int c = blockIdx.y * 64 + 32 * wc + 16 * j + fr;
                float v = acc[i][j][e];
                if (c_bf16) {
                    unsigned short h = f2bf(v);
                    ((unsigned short*)Cp)[(size_t)r * ldc + c] = h;
                    Clo[(size_t)r * ldc + c] = f2bf(v - bf2f(h));
                } else {
                    ((float*)Cp)[(size_t)r * ldc + c] = v;
                }
            }
}

// ---------------- K5: fused attn, scalar-fp32 PV ----------------
__global__ __launch_bounds__(256) void attn_fused(const unsigned short* __restrict__ projh,
                                                  const unsigned short* __restrict__ projl,
                                                  const float* __restrict__ aarr,
                                                  const float* __restrict__ marr,
                                                  const float* __restrict__ csum,
                                                  const float* __restrict__ lnw,
                                                  unsigned short* __restrict__ hout,
                                                  unsigned short* __restrict__ hout_lo) {
    __shared__ __attribute__((aligned(16))) unsigned short Klh[32 * 136];
    __shared__ __attribute__((aligned(16))) unsigned short Kll[32 * 136];
    __shared__ __attribute__((aligned(16))) float Vf[32 * 132];
    __shared__ __attribute__((aligned(16))) float Pf[4][16 * 36];
    __shared__ float al[32];

    const int blk = blockIdx.x;           // 512 = 16 bh * 32 qt
    const int qt = blk & 31, bh = blk >> 5;
    const int b = bh >> 3, h = bh & 7;
    const int tid = threadIdx.x, lane = tid & 63, w = tid >> 6;
    const int fr = lane & 15, fg = lane >> 4;
    const int q0 = qt * 64;

    // ---- QK-phase per-lane state ----
    bf16x8 qfh[4], qfl[4];
    {
        const size_t qoff = (size_t)(b * 2048 + q0 + 16 * w + fr) * 2304 + h * 128;
#pragma unroll
        for (int ks = 0; ks < 4; ks++) {
            qfh[ks] = __builtin_bit_cast(bf16x8, *(const us8*)(projh + qoff + ks * 32 + fg * 8));
            qfl[ks] = __builtin_bit_cast(bf16x8, *(const us8*)(projl + qoff + ks * 32 + fg * 8));
        }
    }
    float maqk[4];
#pragma unroll
    for (int r = 0; r < 4; r++)
        maqk[r] = marr[(size_t)bh * 2048 + q0 + 16 * w + fg * 4 + r];

    // ---- PV-phase per-lane state ----
    const int rpv = lane >> 2;            // 0..15 row within wave tile
    const int cb = (lane & 3) * 32;       // channel block 0/32/64/96
    const int sgpv = q0 + 16 * w + rpv;
    const float cs_pv = csum[(size_t)bh * 2048 + sgpv];
    const float ma_pv = marr[(size_t)bh * 2048 + sgpv];
    f32x4 accs[8] = {};
    float b_run = 0.f;

    // staging ids
    const int kr = tid >> 3, kc = (tid & 7) * 16;
    const int vrow = tid >> 3, vcol = (tid & 7) * 16;
    const size_t kbase = (size_t)(b * 2048) * 2304 + 1024;
    const size_t vgbase = (size_t)(b * 2048) * 2304 + 1152;

    const int nt = 2 * qt + 2;
    for (int kt = 0; kt < nt; kt++) {
        const int t0 = kt * 32;
        const size_t ko = kbase + (size_t)(t0 + kr) * 2304 + kc;
        const size_t vo = vgbase + (size_t)(t0 + vrow) * 2304 + vcol;
        us8 kh0 = *(const us8*)(projh + ko);
        us8 kh1 = *(const us8*)(projh + ko + 8);
        us8 kl0 = *(const us8*)(projl + ko);
        us8 kl1 = *(const us8*)(projl + ko + 8);
        us8 vh0 = *(const us8*)(projh + vo);
        us8 vh1 = *(const us8*)(projh + vo + 8);
        us8 vl0 = *(const us8*)(projl + vo);
        us8 vl1 = *(const us8*)(projl + vo + 8);
        float a_st = (tid < 32) ? aarr[(size_t)bh * 2048 + t0 + tid] : 0.f;
        __syncthreads();
        *(us8*)&Klh[kr * 136 + kc] = kh0;
        *(us8*)&Klh[kr * 136 + kc + 8] = kh1;
        *(us8*)&Kll[kr * 136 + kc] = kl0;
        *(us8*)&Kll[kr * 136 + kc + 8] = kl1;
        {
            f32x4 vv0, vv1, vv2, vv3;
#pragma unroll
            for (int e = 0; e < 4; e++) {
                vv0[e] = bf2f(vh0[e]) + bf2f(vl0[e]);
                vv1[e] = bf2f(vh0[4 + e]) + bf2f(vl0[4 + e]);
                vv2[e] = bf2f(vh1[e]) + bf2f(vl1[e]);
                vv3[e] = bf2f(vh1[4 + e]) + bf2f(vl1[4 + e]);
            }
            float* vd = &Vf[vrow * 132 + vcol];
            *(f32x4*)(vd + 0) = vv0;
            *(f32x4*)(vd + 4) = vv1;
            *(f32x4*)(vd + 8) = vv2;
            *(f32x4*)(vd + 12) = vv3;
        }
        if (tid < 32) al[tid] = a_st;
        __syncthreads();

        // QK^T 3-product MFMA, two 16-key subtiles; P final-valued via prefix-max
#pragma unroll
        for (int j = 0; j < 2; j++) {
            f32x4 sf = {};
#pragma unroll
            for (int ks = 0; ks < 4; ks++) {
                bf16x8 kfh = __builtin_bit_cast(bf16x8, *(const us8*)&Klh[(j * 16 + fr) * 136 + ks * 32 + fg * 8]);
                bf16x8 kfl = __builtin_bit_cast(bf16x8, *(const us8*)&Kll[(j * 16 + fr) * 136 + ks * 32 + fg * 8]);
                sf = mfma16(qfh[ks], kfh, sf);
                sf = mfma16(qfh[ks], kfl, sf);
                sf = mfma16(qfl[ks], kfh, sf);
            }
            const float atj = al[j * 16 + fr];
            const int key = t0 + j * 16 + fr;
#pragma unroll
            for (int r = 0; r < 4; r++) {
                const int sg = q0 + 16 * w + fg * 4 + r;
                float p = (key <= sg) ? sf[r] * __expf(atj - maqk[r]) : 0.f;
                Pf[w][(fg * 4 + r) * 36 + j * 16 + fr] = p;
            }
        }
        __asm__ volatile("s_waitcnt lgkmcnt(0)" ::: "memory");
        __builtin_amdgcn_sched_barrier(0);

        // scalar-fp32 PV: row rpv, channels cb..cb+31
        {
            const float* pr = &Pf[w][rpv * 36];
#pragma unroll 4
            for (int t = 0; t < 32; t++) {
                float p = pr[t];
                b_run += p;
                const float* vrow_p = &Vf[t * 132 + cb];
#pragma unroll
                for (int k4 = 0; k4 < 8; k4++) {
                    f32x4 vv = *(const f32x4*)(vrow_p + k4 * 4);
                    accs[k4] += p * vv;
                }
            }
        }
    }

    // finalize: n-divide, LayerNorm over 128 channels of row rpv, og gate
    const float nf = __expf(-(cs_pv + ma_pv));
    const float n = fmaxf(fabsf(b_run), nf);
    const float inv = 1.f / (n + 1e-6f);
#pragma unroll
    for (int k4 = 0; k4 < 8; k4++) accs[k4] *= inv;

    float s = 0.f;
#pragma unroll
    for (int k4 = 0; k4 < 8; k4++) s += accs[k4][0] + accs[k4][1] + accs[k4][2] + accs[k4][3];
    s += __shfl_xor(s, 1);
    s += __shfl_xor(s, 2);
    const float mu = s * (1.f / 128.f);
    float vv = 0.f;
#pragma unroll
    for (int k4 = 0; k4 < 8; k4++)
#pragma unroll
        for (int e = 0; e < 4; e++) {
            float d = accs[k4][e] - mu;
            vv += d * d;
        }
    vv += __shfl_xor(vv, 1);
    vv += __shfl_xor(vv, 2);
    const float rstd = rsqrtf(vv * (1.f / 128.f) + 1e-6f);

    const size_t obase = (size_t)(b * 2048 + sgpv) * 2304 + 1280 + h * 128 + cb;
    const size_t hbase = (size_t)(b * 2048 + sgpv) * 1024 + h * 128 + cb;
#pragma unroll
    for (int j = 0; j < 4; j++) {
        us8 ogh = *(const us8*)(projh + obase + j * 8);
        us8 ogl = *(const us8*)(projl + obase + j * 8);
        us8 hi8, lo8;
#pragma unroll
        for (int e = 0; e < 8; e++) {
            const int ce = j * 8 + e;             // 0..31 within lane block
            const float av = accs[ce >> 2][ce & 3];
            const float og = bf2f(ogh[e]) + bf2f(ogl[e]);
            const float sig = 1.f / (1.f + __expf(-og));
            const float hn = (av - mu) * rstd * lnw[h * 128 + cb + ce];
            const float ho = hn * sig;
            unsigned short h1 = f2bf(ho);
            hi8[e] = h1;
            lo8[e] = f2bf(ho - bf2f(h1));
        }
        *(us8*)&hout[hbase + j * 8] = hi8;
        *(us8*)&hout_lo[hbase + j * 8] = lo8;
    }
}

// ---------------------------------------------------------------------------
extern "C" void kernel_launch(void* const* d_in, const int* in_sizes, int n_in,
                              void* d_out, int out_size, void* d_ws, size_t ws_size,
                              hipStream_t stream) {
    (void)in_sizes; (void)n_in; (void)out_size; (void)ws_size;
    const float* x    = (const float*)d_in[0];
    const float* Wq   = (const float*)d_in[1];
    const float* Wk   = (const float*)d_in[2];
    const float* Wv   = (const float*)d_in[3];
    const float* Wog  = (const float*)d_in[4];
    const float* Wi   = (const float*)d_in[5];
    const float* bi   = (const float*)d_in[6];
    const float* Wf   = (const float*)d_in[7];
    const float* bfb  = (const float*)d_in[8];
    const float* lnw  = (const float*)d_in[9];
    const float* Wout = (const float*)d_in[10];

    char* p = (char*)d_ws;
    auto carve = [&](size_t bytes) -> char* {
        char* r = p;
        p += (bytes + 255) & ~(size_t)255;
        return r;
    };
    unsigned short* x_hi   = (unsigned short*)carve(4194304ull * 2);
    unsigned short* x_lo   = (unsigned short*)carve(4194304ull * 2);
    unsigned short* wc_hi  = (unsigned short*)carve(2359296ull * 2);
    unsigned short* wc_lo  = (unsigned short*)carve(2359296ull * 2);
    unsigned short* wo_hi  = (unsigned short*)carve(1048576ull * 2);
    unsigned short* wo_lo  = (unsigned short*)carve(1048576ull * 2);
    unsigned short* pr_hi  = (unsigned short*)carve(4096ull * 2304 * 2);
    unsigned short* pr_lo  = (unsigned short*)carve(4096ull * 2304 * 2);
    float* ipre    = (float*)carve(32768ull * 4);
    float* lgf_buf = (float*)carve(32768ull * 4);
    float* csum    = (float*)carve(32768ull * 4);
    float* aarr    = (float*)carve(32768ull * 4);
    float* marr    = (float*)carve(32768ull * 4);
    // hout aliases the x split buffers (dead after K3)
    unsigned short* ho_hi = x_hi;
    unsigned short* ho_lo = x_lo;

    k_split_bf16<<<16384, 256, 0, stream>>>(x, x_hi, x_lo, 4194304);
    build_wcat<<<(2359296 + 255) / 256, 256, 0, stream>>>(Wq, Wk, Wv, Wog, wc_hi, wc_lo);
    k_split_bf16<<<4096, 256, 0, stream>>>(Wout, wo_hi, wo_lo, 1048576);
    gates_kernel<<<4096, 256, 0, stream>>>(x, Wi, bi, Wf, bfb, ipre, lgf_buf);
    scan_kernel<<<16, 64, 0, stream>>>(ipre, lgf_buf, csum, aarr, marr);
    gemm_bt3<<<dim3(64, 36), 256, 0, stream>>>(x_hi, x_lo, wc_hi, wc_lo, pr_hi, pr_lo, 1024, 2304, 1);
    attn_fused<<<512, 256, 0, stream>>>(pr_hi, pr_lo, aarr, marr, csum, lnw, ho_hi, ho_lo);
    gemm_bt3<<<dim3(64, 16), 256, 0, stream>>>(ho_hi, ho_lo, wo_hi, wo_lo, d_out, nullptr, 1024, 1024, 0);
}

// Round 5
// 336.288 us; speedup vs baseline: 2.3876x; 2.3876x over previous
//
#include <hip/hip_runtime.h>

// ---------------------------------------------------------------------------
// mLSTM block, MI355X. B=2,S=2048,D=1024,NH=8,DH=128.
// v4: MFMA PV restored (P via f32 LDS + proven fence), K-stride 148, prefetch.
//   K0  split x, Wout -> hi/lo ; Wcat hi/lo [2304,1024]
//   K1  gates: i_pre, log_sigmoid(f_pre)  (fp32)
//   K2  scan per (b,h): csum[s], a[t]=i[t]-csum[t], ma[t]=prefixmax(a)
//   K3  GEMM3 proj = (x_hi+x_lo)(W_hi+W_lo)^T -> proj hi/lo
//   K4  vT transpose (hi/lo)
//   K5  fused: MFMA QK^T (3-prod) -> P=s*exp(a-ma) -> MFMA PV (3-prod)
//       -> n-divide -> LayerNorm -> sigmoid(og) -> hout hi/lo
//   K6  GEMM3 y -> f32
// ---------------------------------------------------------------------------

typedef __bf16 bf16x8 __attribute__((ext_vector_type(8)));
typedef float f32x4 __attribute__((ext_vector_type(4)));
typedef unsigned short us8 __attribute__((ext_vector_type(8)));

__device__ __forceinline__ unsigned short f2bf(float f) {
    unsigned int u = __builtin_bit_cast(unsigned int, f);
    unsigned int r = u + 0x7fffu + ((u >> 16) & 1u);
    return (unsigned short)(r >> 16);
}
__device__ __forceinline__ float bf2f(unsigned short h) {
    unsigned int u = ((unsigned int)h) << 16;
    return __builtin_bit_cast(float, u);
}
__device__ __forceinline__ f32x4 mfma16(bf16x8 a, bf16x8 b, f32x4 c) {
    return __builtin_amdgcn_mfma_f32_16x16x32_bf16(a, b, c, 0, 0, 0);
}

// ---------------- K0 ----------------
__global__ __launch_bounds__(256) void k_split_bf16(const float* __restrict__ in,
                                                    unsigned short* __restrict__ hi,
                                                    unsigned short* __restrict__ lo, int n) {
    int i = blockIdx.x * 256 + threadIdx.x;
    if (i < n) {
        float f = in[i];
        unsigned short h = f2bf(f);
        hi[i] = h;
        lo[i] = f2bf(f - bf2f(h));
    }
}

__global__ __launch_bounds__(256) void build_wcat(const float* __restrict__ Wq,
                                                  const float* __restrict__ Wk,
                                                  const float* __restrict__ Wv,
                                                  const float* __restrict__ Wog,
                                                  unsigned short* __restrict__ wh,
                                                  unsigned short* __restrict__ wl) {
    int idx = blockIdx.x * 256 + threadIdx.x;
    if (idx >= 2304 * 1024) return;
    int row = idx >> 10, col = idx & 1023;
    float v;
    if (row < 1024)      v = Wq[(size_t)row * 1024 + col] * 0.08838834764831845f;
    else if (row < 1152) v = Wk[(size_t)(row - 1024) * 1024 + col];
    else if (row < 1280) v = Wv[(size_t)(row - 1152) * 1024 + col];
    else                 v = Wog[(size_t)(row - 1280) * 1024 + col];
    unsigned short h = f2bf(v);
    wh[idx] = h;
    wl[idx] = f2bf(v - bf2f(h));
}

// ---------------- K1: gates ----------------
__global__ __launch_bounds__(256) void gates_kernel(const float* __restrict__ x,
                                                    const float* __restrict__ Wi,
                                                    const float* __restrict__ bi,
                                                    const float* __restrict__ Wf,
                                                    const float* __restrict__ bfb,
                                                    float* __restrict__ ipre,
                                                    float* __restrict__ lgf) {
    int bs = blockIdx.x;
    int b = bs >> 11, s = bs & 2047;
    const float* xr = x + (size_t)bs * 1024;
    int lane = threadIdx.x & 63, w = threadIdx.x >> 6;
    const float* W = (w < 2) ? Wi : Wf;
    int h0 = (w & 1) * 4;
    float dot0 = 0.f, dot1 = 0.f, dot2 = 0.f, dot3 = 0.f;
    for (int i = lane; i < 1024; i += 64) {
        float xv = xr[i];
        dot0 += xv * W[(size_t)(h0 + 0) * 1024 + i];
        dot1 += xv * W[(size_t)(h0 + 1) * 1024 + i];
        dot2 += xv * W[(size_t)(h0 + 2) * 1024 + i];
        dot3 += xv * W[(size_t)(h0 + 3) * 1024 + i];
    }
#pragma unroll
    for (int o = 32; o; o >>= 1) {
        dot0 += __shfl_xor(dot0, o);
        dot1 += __shfl_xor(dot1, o);
        dot2 += __shfl_xor(dot2, o);
        dot3 += __shfl_xor(dot3, o);
    }
    if (lane == 0) {
        float d[4] = {dot0, dot1, dot2, dot3};
#pragma unroll
        for (int j = 0; j < 4; j++) {
            int hh = h0 + j;
            if (w < 2) {
                float z = d[j] + bi[hh];
                z = 15.f * tanhf(z * (1.f / 15.f));
                ipre[((size_t)b * 8 + hh) * 2048 + s] = z;
            } else {
                float z = d[j] + bfb[hh];
                z = 15.f * tanhf(z * (1.f / 15.f));
                lgf[((size_t)b * 8 + hh) * 2048 + s] = fminf(z, 0.f) - log1pf(expf(-fabsf(z)));
            }
        }
    }
}

// ---------------- K2: scan (csum, a, prefix-max of a) ----------------
__global__ void scan_kernel(const float* __restrict__ ipre, const float* __restrict__ lgf,
                            float* __restrict__ csum, float* __restrict__ aarr,
                            float* __restrict__ marr) {
    int bh = blockIdx.x;
    int lane = threadIdx.x;
    const float* lf = lgf + (size_t)bh * 2048;
    const float* ip = ipre + (size_t)bh * 2048;
    float* cs = csum + (size_t)bh * 2048;
    float* aa = aarr + (size_t)bh * 2048;
    float* mm = marr + (size_t)bh * 2048;
    float carry = 0.f;
    float carrym = -1e30f;
    for (int c = 0; c < 32; c++) {
        float v = lf[c * 64 + lane];
#pragma unroll
        for (int o = 1; o < 64; o <<= 1) {
            float t = __shfl_up(v, o);
            if (lane >= o) v += t;
        }
        float cval = carry + v;
        cs[c * 64 + lane] = cval;
        float a = ip[c * 64 + lane] - cval;
        aa[c * 64 + lane] = a;
        float mv = a;
#pragma unroll
        for (int o = 1; o < 64; o <<= 1) {
            float t = __shfl_up(mv, o);
            if (lane >= o) mv = fmaxf(mv, t);
        }
        float mval = fmaxf(carrym, mv);
        mm[c * 64 + lane] = mval;
        carry = __shfl(cval, 63);
        carrym = __shfl(mval, 63);
    }
}

// ---- K3/K6: 3-product GEMM  C = (Ah+Al)(Bh+Bl)^T (drop Al*Bl), f32 acc ----
__global__ __launch_bounds__(256) void gemm_bt3(const unsigned short* __restrict__ Ah,
                                                const unsigned short* __restrict__ Al,
                                                const unsigned short* __restrict__ Bh,
                                                const unsigned short* __restrict__ Bl,
                                                void* __restrict__ Cp,
                                                unsigned short* __restrict__ Clo,
                                                int K, int ldc, int c_bf16) {
    __shared__ __attribute__((aligned(16))) unsigned short Ash[64 * 40];
    __shared__ __attribute__((aligned(16))) unsigned short Asl[64 * 40];
    __shared__ __attribute__((aligned(16))) unsigned short Bsh[64 * 40];
    __shared__ __attribute__((aligned(16))) unsigned short Bsl[64 * 40];
    const int tid = threadIdx.x;
    const int lane = tid & 63, wv = tid >> 6;
    const int wr = wv >> 1, wc = wv & 1;
    const int fr = lane & 15, fg = lane >> 4;
    const int srow = tid >> 2, scol = (tid & 3) * 8;
    const size_t aoff = (size_t)(blockIdx.x * 64 + srow) * K + scol;
    const size_t boff = (size_t)(blockIdx.y * 64 + srow) * K + scol;
    f32x4 acc[2][2] = {};
    for (int kt = 0; kt < K; kt += 32) {
        us8 avh = *(const us8*)(Ah + aoff + kt);
        us8 avl = *(const us8*)(Al + aoff + kt);
        us8 bvh = *(const us8*)(Bh + boff + kt);
        us8 bvl = *(const us8*)(Bl + boff + kt);
        __syncthreads();
        *(us8*)&Ash[srow * 40 + scol] = avh;
        *(us8*)&Asl[srow * 40 + scol] = avl;
        *(us8*)&Bsh[srow * 40 + scol] = bvh;
        *(us8*)&Bsl[srow * 40 + scol] = bvl;
        __syncthreads();
        bf16x8 afh[2], afl[2], bfh[2], bfl[2];
#pragma unroll
        for (int i = 0; i < 2; i++) {
            afh[i] = __builtin_bit_cast(bf16x8, *(const us8*)&Ash[(32 * wr + 16 * i + fr) * 40 + fg * 8]);
            afl[i] = __builtin_bit_cast(bf16x8, *(const us8*)&Asl[(32 * wr + 16 * i + fr) * 40 + fg * 8]);
        }
#pragma unroll
        for (int j = 0; j < 2; j++) {
            bfh[j] = __builtin_bit_cast(bf16x8, *(const us8*)&Bsh[(32 * wc + 16 * j + fr) * 40 + fg * 8]);
            bfl[j] = __builtin_bit_cast(bf16x8, *(const us8*)&Bsl[(32 * wc + 16 * j + fr) * 40 + fg * 8]);
        }
#pragma unroll
        for (int i = 0; i < 2; i++)
#pragma unroll
            for (int j = 0; j < 2; j++) {
                acc[i][j] = mfma16(afh[i], bfh[j], acc[i][j]);
                acc[i][j] = mfma16(afh[i], bfl[j], acc[i][j]);
                acc[i][j] = mfma16(afl[i], bfh[j], acc[i][j]);
            }
    }
#pragma unroll
    for (int i = 0; i < 2; i++)
#pragma unroll
        for (int j = 0; j < 2; j++)
#pragma unroll
            for (int e = 0; e < 4; e++) {
                int r = blockIdx.x * 64 + 32 * wr + 16 * i + fg * 4 + e;
                int c = blockIdx.y * 64 + 32 * wc + 16 * j + fr;
                float v = acc[i][j][e];
                if (c_bf16) {
                    unsigned short h = f2bf(v);
                    ((unsigned short*)Cp)[(size_t)r * ldc + c] = h;
                    Clo[(size_t)r * ldc + c] = f2bf(v - bf2f(h));
                } else {
                    ((float*)Cp)[(size_t)r * ldc + c] = v;
                }
            }
}

// ---------------- K4: vT[b][c][s] = proj[b*2048+s][1152+c] ----------------
__global__ __launch_bounds__(256) void make_vt(const unsigned short* __restrict__ ph,
                                               const unsigned short* __restrict__ pl,
                                               unsigned short* __restrict__ vTh,
                                               unsigned short* __restrict__ vTl) {
    int i = blockIdx.x * 256 + threadIdx.x;
    if (i >= 524288) return;
    int s = i & 2047, c = (i >> 11) & 127, b = i >> 18;
    size_t src = ((size_t)(b * 2048 + s)) * 2304 + 1152 + c;
    vTh[i] = ph[src];
    vTl[i] = pl[src];
}

// ---------------- K5: fused attn, MFMA QK + MFMA PV ----------------
__global__ __launch_bounds__(256) void attn_fused(const unsigned short* __restrict__ projh,
                                                  const unsigned short* __restrict__ projl,
                                                  const unsigned short* __restrict__ vTh,
                                                  const unsigned short* __restrict__ vTl,
                                                  const float* __restrict__ aarr,
                                                  const float* __restrict__ marr,
                                                  const float* __restrict__ csum,
                                                  const float* __restrict__ lnw,
                                                  unsigned short* __restrict__ hout,
                                                  unsigned short* __restrict__ hout_lo) {
    __shared__ __attribute__((aligned(16))) unsigned short Klh[32 * 148];
    __shared__ __attribute__((aligned(16))) unsigned short Kll[32 * 148];
    __shared__ __attribute__((aligned(16))) unsigned short Vlh[128 * 40];
    __shared__ __attribute__((aligned(16))) unsigned short Vll[128 * 40];
    __shared__ __attribute__((aligned(16))) float Pf[4][16 * 36];
    __shared__ float al[32];

    const int blk = blockIdx.x;           // 512 = 16 bh * 32 qt
    const int qt = blk & 31, bh = blk >> 5;
    const int b = bh >> 3, h = bh & 7;
    const int tid = threadIdx.x, lane = tid & 63, w = tid >> 6;
    const int fr = lane & 15, fg = lane >> 4;
    const int q0 = qt * 64;

    // Q fragments hi/lo
    bf16x8 qfh[4], qfl[4];
    {
        const size_t qoff = (size_t)(b * 2048 + q0 + 16 * w + fr) * 2304 + h * 128;
#pragma unroll
        for (int ks = 0; ks < 4; ks++) {
            qfh[ks] = __builtin_bit_cast(bf16x8, *(const us8*)(projh + qoff + ks * 32 + fg * 8));
            qfl[ks] = __builtin_bit_cast(bf16x8, *(const us8*)(projl + qoff + ks * 32 + fg * 8));
        }
    }
    float maqk[4];
#pragma unroll
    for (int r = 0; r < 4; r++)
        maqk[r] = marr[(size_t)bh * 2048 + q0 + 16 * w + fg * 4 + r];

    // all-ones B fragment (for row sums via MFMA)
    us8 onesu;
#pragma unroll
    for (int e = 0; e < 8; e++) onesu[e] = 0x3F80;
    const bf16x8 onesf = __builtin_bit_cast(bf16x8, onesu);

    f32x4 acc[8] = {};
    f32x4 acc_b = {};

    const int kr = tid >> 3, kc = (tid & 7) * 16;   // K staging
    const int vr = tid >> 1, vc = (tid & 1) * 16;   // V staging (from vT)
    const size_t kbase = (size_t)(b * 2048) * 2304 + 1024;
    const size_t vbase = (size_t)b * 128 * 2048;

    const int nt = 2 * qt + 2;
    us8 kh0, kh1, kl0, kl1, vh0, vh1, vl0, vl1;
    float a_st;
#define LOADT(T0)                                                              \
    {                                                                          \
        const size_t ko = kbase + (size_t)((T0) + kr) * 2304 + kc;             \
        const size_t vo = vbase + (size_t)vr * 2048 + (T0) + vc;               \
        kh0 = *(const us8*)(projh + ko);                                       \
        kh1 = *(const us8*)(projh + ko + 8);                                   \
        kl0 = *(const us8*)(projl + ko);                                       \
        kl1 = *(const us8*)(projl + ko + 8);                                   \
        vh0 = *(const us8*)(vTh + vo);                                         \
        vh1 = *(const us8*)(vTh + vo + 8);                                     \
        vl0 = *(const us8*)(vTl + vo);                                         \
        vl1 = *(const us8*)(vTl + vo + 8);                                     \
        a_st = (tid < 32) ? aarr[(size_t)bh * 2048 + (T0) + tid] : 0.f;        \
    }

    LOADT(0);
    for (int kt = 0; kt < nt; kt++) {
        const int t0 = kt * 32;
        __syncthreads();
        *(us8*)&Klh[kr * 148 + kc] = kh0;
        *(us8*)&Klh[kr * 148 + kc + 8] = kh1;
        *(us8*)&Kll[kr * 148 + kc] = kl0;
        *(us8*)&Kll[kr * 148 + kc + 8] = kl1;
        *(us8*)&Vlh[vr * 40 + vc] = vh0;
        *(us8*)&Vlh[vr * 40 + vc + 8] = vh1;
        *(us8*)&Vll[vr * 40 + vc] = vl0;
        *(us8*)&Vll[vr * 40 + vc + 8] = vl1;
        if (tid < 32) al[tid] = a_st;
        __syncthreads();
        if (kt + 1 < nt) LOADT(t0 + 32);

        const bool full = (t0 + 31 <= q0 + 16 * w);
        // QK^T 3-product; P final-valued via exact prefix-max; write f32 P
#pragma unroll
        for (int j = 0; j < 2; j++) {
            f32x4 sf = {};
#pragma unroll
            for (int ks = 0; ks < 4; ks++) {
                bf16x8 kfh = __builtin_bit_cast(bf16x8, *(const us8*)&Klh[(j * 16 + fr) * 148 + ks * 32 + fg * 8]);
                bf16x8 kfl = __builtin_bit_cast(bf16x8, *(const us8*)&Kll[(j * 16 + fr) * 148 + ks * 32 + fg * 8]);
                sf = mfma16(qfh[ks], kfh, sf);
                sf = mfma16(qfh[ks], kfl, sf);
                sf = mfma16(qfl[ks], kfh, sf);
            }
            const float atj = al[j * 16 + fr];
            const int key = t0 + j * 16 + fr;
#pragma unroll
            for (int r = 0; r < 4; r++) {
                float p = sf[r] * __expf(atj - maqk[r]);
                if (!full && key > q0 + 16 * w + fg * 4 + r) p = 0.f;
                Pf[w][(fg * 4 + r) * 36 + j * 16 + fr] = p;
            }
        }
        __asm__ volatile("s_waitcnt lgkmcnt(0)" ::: "memory");
        __builtin_amdgcn_sched_barrier(0);

        // transposed read -> A-frag, convert to bf16 hi/lo in-register
        f32x4 pa = *(const f32x4*)&Pf[w][fr * 36 + fg * 8];
        f32x4 pb = *(const f32x4*)&Pf[w][fr * 36 + fg * 8 + 4];
        us8 phu, plu;
#pragma unroll
        for (int e = 0; e < 4; e++) {
            unsigned short hh = f2bf(pa[e]);
            phu[e] = hh;
            plu[e] = f2bf(pa[e] - bf2f(hh));
            unsigned short h2 = f2bf(pb[e]);
            phu[4 + e] = h2;
            plu[4 + e] = f2bf(pb[e] - bf2f(h2));
        }
        const bf16x8 pfh = __builtin_bit_cast(bf16x8, phu);
        const bf16x8 pfl = __builtin_bit_cast(bf16x8, plu);

        acc_b = mfma16(pfh, onesf, acc_b);
        acc_b = mfma16(pfl, onesf, acc_b);
#pragma unroll
        for (int jb = 0; jb < 8; jb++) {
            bf16x8 vfh = __builtin_bit_cast(bf16x8, *(const us8*)&Vlh[(jb * 16 + fr) * 40 + fg * 8]);
            bf16x8 vfl = __builtin_bit_cast(bf16x8, *(const us8*)&Vll[(jb * 16 + fr) * 40 + fg * 8]);
            acc[jb] = mfma16(pfh, vfh, acc[jb]);
            acc[jb] = mfma16(pfh, vfl, acc[jb]);
            acc[jb] = mfma16(pfl, vfh, acc[jb]);
        }
    }
#undef LOADT

    // finalize: n-divide, LayerNorm, og gate
    float inv[4];
#pragma unroll
    for (int r = 0; r < 4; r++) {
        const int sg = q0 + 16 * w + fg * 4 + r;
        const float cs = csum[(size_t)bh * 2048 + sg];
        const float nf = __expf(-(cs + maqk[r]));
        const float n = fmaxf(fabsf(acc_b[r]), nf);
        inv[r] = 1.f / (n + 1e-6f);
    }
    f32x4 invv;
    invv[0] = inv[0]; invv[1] = inv[1]; invv[2] = inv[2]; invv[3] = inv[3];
#pragma unroll
    for (int jb = 0; jb < 8; jb++) acc[jb] *= invv;

    float mu[4] = {0.f, 0.f, 0.f, 0.f};
#pragma unroll
    for (int jb = 0; jb < 8; jb++)
#pragma unroll
        for (int r = 0; r < 4; r++) mu[r] += acc[jb][r];
#pragma unroll
    for (int r = 0; r < 4; r++) {
        float t = mu[r];
        t += __shfl_xor(t, 1); t += __shfl_xor(t, 2); t += __shfl_xor(t, 4); t += __shfl_xor(t, 8);
        mu[r] = t * (1.f / 128.f);
    }
    float var[4] = {0.f, 0.f, 0.f, 0.f};
#pragma unroll
    for (int jb = 0; jb < 8; jb++)
#pragma unroll
        for (int r = 0; r < 4; r++) {
            float d = acc[jb][r] - mu[r];
            var[r] += d * d;
        }
    float rstd[4];
#pragma unroll
    for (int r = 0; r < 4; r++) {
        float t = var[r];
        t += __shfl_xor(t, 1); t += __shfl_xor(t, 2); t += __shfl_xor(t, 4); t += __shfl_xor(t, 8);
        rstd[r] = rsqrtf(t * (1.f / 128.f) + 1e-6f);
    }

#pragma unroll
    for (int jb = 0; jb < 8; jb++) {
        const int c = h * 128 + jb * 16 + fr;
        const float lw = lnw[c];
#pragma unroll
        for (int r = 0; r < 4; r++) {
            const int sg = q0 + 16 * w + fg * 4 + r;
            const size_t ogo = (size_t)(b * 2048 + sg) * 2304 + 1280 + c;
            const float og = bf2f(projh[ogo]) + bf2f(projl[ogo]);
            const float sig = 1.f / (1.f + __expf(-og));
            const float hn = (acc[jb][r] - mu[r]) * rstd[r] * lw;
            const float ho = hn * sig;
            unsigned short h1 = f2bf(ho);
            hout[(size_t)(b * 2048 + sg) * 1024 + c] = h1;
            hout_lo[(size_t)(b * 2048 + sg) * 1024 + c] = f2bf(ho - bf2f(h1));
        }
    }
}

// ---------------------------------------------------------------------------
extern "C" void kernel_launch(void* const* d_in, const int* in_sizes, int n_in,
                              void* d_out, int out_size, void* d_ws, size_t ws_size,
                              hipStream_t stream) {
    (void)in_sizes; (void)n_in; (void)out_size; (void)ws_size;
    const float* x    = (const float*)d_in[0];
    const float* Wq   = (const float*)d_in[1];
    const float* Wk   = (const float*)d_in[2];
    const float* Wv   = (const float*)d_in[3];
    const float* Wog  = (const float*)d_in[4];
    const float* Wi   = (const float*)d_in[5];
    const float* bi   = (const float*)d_in[6];
    const float* Wf   = (const float*)d_in[7];
    const float* bfb  = (const float*)d_in[8];
    const float* lnw  = (const float*)d_in[9];
    const float* Wout = (const float*)d_in[10];

    char* p = (char*)d_ws;
    auto carve = [&](size_t bytes) -> char* {
        char* r = p;
        p += (bytes + 255) & ~(size_t)255;
        return r;
    };
    unsigned short* x_hi   = (unsigned short*)carve(4194304ull * 2);
    unsigned short* x_lo   = (unsigned short*)carve(4194304ull * 2);
    unsigned short* wc_hi  = (unsigned short*)carve(2359296ull * 2);
    unsigned short* wc_lo  = (unsigned short*)carve(2359296ull * 2);
    unsigned short* wo_hi  = (unsigned short*)carve(1048576ull * 2);
    unsigned short* wo_lo  = (unsigned short*)carve(1048576ull * 2);
    unsigned short* pr_hi  = (unsigned short*)carve(4096ull * 2304 * 2);
    unsigned short* pr_lo  = (unsigned short*)carve(4096ull * 2304 * 2);
    unsigned short* vT_hi  = (unsigned short*)carve(524288ull * 2);
    unsigned short* vT_lo  = (unsigned short*)carve(524288ull * 2);
    float* ipre    = (float*)carve(32768ull * 4);
    float* lgf_buf = (float*)carve(32768ull * 4);
    float* csum    = (float*)carve(32768ull * 4);
    float* aarr    = (float*)carve(32768ull * 4);
    float* marr    = (float*)carve(32768ull * 4);
    // hout aliases the x split buffers (dead after K3)
    unsigned short* ho_hi = x_hi;
    unsigned short* ho_lo = x_lo;

    k_split_bf16<<<16384, 256, 0, stream>>>(x, x_hi, x_lo, 4194304);
    build_wcat<<<(2359296 + 255) / 256, 256, 0, stream>>>(Wq, Wk, Wv, Wog, wc_hi, wc_lo);
    k_split_bf16<<<4096, 256, 0, stream>>>(Wout, wo_hi, wo_lo, 1048576);
    gates_kernel<<<4096, 256, 0, stream>>>(x, Wi, bi, Wf, bfb, ipre, lgf_buf);
    scan_kernel<<<16, 64, 0, stream>>>(ipre, lgf_buf, csum, aarr, marr);
    gemm_bt3<<<dim3(64, 36), 256, 0, stream>>>(x_hi, x_lo, wc_hi, wc_lo, pr_hi, pr_lo, 1024, 2304, 1);
    make_vt<<<2048, 256, 0, stream>>>(pr_hi, pr_lo, vT_hi, vT_lo);
    attn_fused<<<512, 256, 0, stream>>>(pr_hi, pr_lo, vT_hi, vT_lo, aarr, marr, csum, lnw, ho_hi, ho_lo);
    gemm_bt3<<<dim3(64, 16), 256, 0, stream>>>(ho_hi, ho_lo, wo_hi, wo_lo, d_out, nullptr, 1024, 1024, 0);
}